// Round 2
// baseline (2091.731 us; speedup 1.0000x reference)
//
#include <hip/hip_runtime.h>
#include <hip/hip_bf16.h>
#include <stdio.h>

#define DIM 2048
#define HID 2730
#define HID_PAD 2816   // 22*128, zero-padded
#define NE 8
#define NTOK 8192      // B*T
#define NROWS 24576    // 16384 expert-assignment rows + 8192 shared rows

typedef __bf16 v8bf __attribute__((ext_vector_type(8)));
typedef float v4f  __attribute__((ext_vector_type(4)));

// async global->LDS, 16B per lane, wave-uniform LDS base + lane*16 (m97/m104 semantics)
__device__ __forceinline__ void gload16(const void* g, void* l){
  __builtin_amdgcn_global_load_lds((const __attribute__((address_space(1))) void*)g,
                                   (__attribute__((address_space(3))) void*)l, 16, 0, 0);
}

// ---------------- small utility kernels ----------------

__global__ void moe_zero_i(int* __restrict__ p, int n){
  int i = threadIdx.x;
  if (i < n) p[i] = 0;
}

__global__ void moe_cast_x(const float* __restrict__ x, __hip_bfloat16* __restrict__ xb){
  int i = (blockIdx.x*blockDim.x + threadIdx.x)*4;
  float4 v = *reinterpret_cast<const float4*>(x + i);
  __hip_bfloat16 o[4];
  o[0]=__float2bfloat16(v.x); o[1]=__float2bfloat16(v.y);
  o[2]=__float2bfloat16(v.z); o[3]=__float2bfloat16(v.w);
  unsigned long long u; __builtin_memcpy(&u, o, 8);
  *reinterpret_cast<unsigned long long*>(xb + i) = u;
}

// transpose-cast fp32 -> bf16, B^T layout with zero padding.
__global__ void moe_tcast(const float* __restrict__ srcE, const float* __restrict__ srcS,
                          __hip_bfloat16* __restrict__ dst, int R, int C, int Cp, int Rp){
  int e = blockIdx.z;
  const float* src = (e < NE) ? (srcE + (size_t)e*R*C) : srcS;
  __hip_bfloat16* d = dst + (size_t)e*Cp*Rp;
  __shared__ float tile[32][33];
  int c0 = blockIdx.x*32, r0 = blockIdx.y*32;
  #pragma unroll
  for (int i=0;i<4;i++){
    int r = r0 + threadIdx.y + i*8, c = c0 + threadIdx.x;
    float v = (r < R && c < C) ? src[(size_t)r*C + c] : 0.0f;
    tile[threadIdx.y + i*8][threadIdx.x] = v;
  }
  __syncthreads();
  #pragma unroll
  for (int i=0;i<4;i++){
    int c = c0 + threadIdx.y + i*8, r = r0 + threadIdx.x;
    if (c < Cp && r < Rp)
      d[(size_t)c*Rp + r] = __float2bfloat16(tile[threadIdx.x][threadIdx.y + i*8]);
  }
}

// ---------------- router: fp32 logits, softmax, top-2, bucket ----------------

__global__ __launch_bounds__(256) void moe_router(
    const float* __restrict__ x, const float* __restrict__ rw,
    float* __restrict__ topw, int* __restrict__ cnt, int* __restrict__ bucket){
  int wav = threadIdx.x >> 6, lane = threadIdx.x & 63;
  int t = blockIdx.x*4 + wav;
  const float* xr = x + (size_t)t*DIM;
  float a[NE];
  #pragma unroll
  for (int e=0;e<NE;e++) a[e]=0.f;
  for (int d0 = lane; d0 < DIM; d0 += 64){
    float xv = xr[d0];
    const float* rr = rw + d0*NE;
    #pragma unroll
    for (int e=0;e<NE;e++) a[e] += xv * rr[e];
  }
  #pragma unroll
  for (int e=0;e<NE;e++){
    float v = a[e];
    #pragma unroll
    for (int o=32;o>0;o>>=1) v += __shfl_xor(v, o);
    a[e]=v;
  }
  if (lane == 0){
    float m = a[0];
    for (int e=1;e<NE;e++) m = fmaxf(m, a[e]);
    float p[NE];
    for (int e=0;e<NE;e++) p[e] = expf(a[e]-m);
    int e0=0;
    for (int e=1;e<NE;e++) if (p[e] > p[e0]) e0=e;          // ties -> first idx (matches top_k)
    int e1 = (e0==0)?1:0;
    for (int e=0;e<NE;e++) if (e!=e0 && p[e] > p[e1]) e1=e;
    float ss = p[e0]+p[e1];
    topw[t*2]   = p[e0]/ss;
    topw[t*2+1] = p[e1]/ss;
    int p0 = atomicAdd(&cnt[e0],1); bucket[e0*16384 + p0] = t*2;
    int p1 = atomicAdd(&cnt[e1],1); bucket[e1*16384 + p1] = t*2+1;
  }
}

__global__ void moe_prefix(const int* __restrict__ cnt, int* __restrict__ base){
  if (threadIdx.x==0 && blockIdx.x==0){
    int b=0; base[0]=0;
    for (int e=0;e<NE;e++){ b += cnt[e]; base[e+1]=b; }  // base[8] == 16384
    base[9] = base[8] + NTOK;
  }
}

// rows [0,16384): expert assignments (grouped); rows [16384,24576): shared (weight 1)
__global__ void moe_fill(const int* __restrict__ cnt, const int* __restrict__ base,
                         const int* __restrict__ bucket, const float* __restrict__ topw,
                         int* __restrict__ row_token, float* __restrict__ row_weight,
                         int* __restrict__ inv){
  int idx = blockIdx.x*blockDim.x + threadIdx.x;   // 544*256 = 8*16384 + 8192
  if (idx < NE*16384){
    int e = idx >> 14, p = idx & 16383;
    if (p < cnt[e]){
      int slot = bucket[idx];
      int row = base[e] + p;
      row_token[row]  = slot >> 1;
      row_weight[row] = topw[slot];
      inv[slot] = row;
    }
  } else {
    int t = idx - NE*16384;
    row_token[16384 + t]  = t;
    row_weight[16384 + t] = 1.0f;
  }
}

// ---------------- GEMM1: g = silu(Xg @ w1) * (Xg @ w3) ----------------
// 8-phase-style schedule (m201 template, T2+T3+T4+T5): BK=64, 4 phases per K-tile,
// each phase {ds_read quadrant frags | stage 1 half-tile | barrier | lgkm0 | 16 MFMA | barrier}.
// Tile-end wait = vmcnt(4) (A[t+2] in flight), never 0 until tail.
// Staging ledger (tile t): P1->B1[t+1], P2->B3[t+1], P3->A-lo[t+2], P4->A-hi[t+2].
//   WAR-safe: each region's last ds_read completes at its phase's lgkm0, before the
//   post-MFMA barrier that precedes the overwriting stage issue.
//   RAW-safe: at tile-t entry barrier, vmcnt(4) leaves only A[t+1] outstanding.
// Swizzle: row r (64 elems, 8x16B chunks), slot s holds logical chunk s^(r&7); read at
//   slot (ks*4+lq)^(lm&7) -> 2-way bank aliasing (free, m136). SQ_LDS_BANK_CONFLICT=0 verified.

#define BM1 256
#define BN1 128   // per B matrix (x2 mats = 256 output cols effective)
#define NT1 32    // DIM/64

__global__ __launch_bounds__(512, 2) void moe_gemm1(
    const __hip_bfloat16* __restrict__ xb,    // [NTOK][DIM]
    const __hip_bfloat16* __restrict__ w1t,   // [9][HID_PAD][DIM]  (B^T)
    const __hip_bfloat16* __restrict__ w3t,
    const int* __restrict__ row_token,
    const int* __restrict__ base_,            // [10]
    __hip_bfloat16* __restrict__ g)           // [NROWS][HID_PAD]
{
  int e = blockIdx.z;
  int base = base_[e];
  int cnt  = base_[e+1] - base;
  int m0 = blockIdx.y * BM1;
  if (m0 >= cnt) return;
  int n0 = blockIdx.x * BN1;

  __shared__ __align__(16) unsigned short lA [2][BM1][64];   // 64 KB
  __shared__ __align__(16) unsigned short lB1[2][BN1][64];   // 32 KB
  __shared__ __align__(16) unsigned short lB3[2][BN1][64];   // 32 KB
  __shared__ int tok[BM1];

  int tid = threadIdx.x;
  if (tid < BM1){
    int r = m0 + tid;
    tok[tid] = row_token[base + (r < cnt ? r : m0)];
  }
  __syncthreads();

  const __hip_bfloat16* w1e = w1t + (size_t)e*HID_PAD*DIM;
  const __hip_bfloat16* w3e = w3t + (size_t)e*HID_PAD*DIM;

  int wav = tid >> 6, lane = tid & 63;

  // staging geometry: 128-row unit = 1024 chunks; issue k covers chunk k*512+wav*64+lane
  int rr = (wav*64 + lane) >> 3;                         // [0,64)
  int qq = (((wav*64 + lane) & 7) ^ (rr & 7)) * 8;       // pre-swizzled element offset

  const __hip_bfloat16* aP0 = xb + (size_t)tok[rr      ]*DIM + qq;
  const __hip_bfloat16* aP1 = xb + (size_t)tok[rr +  64]*DIM + qq;
  const __hip_bfloat16* aP2 = xb + (size_t)tok[rr + 128]*DIM + qq;
  const __hip_bfloat16* aP3 = xb + (size_t)tok[rr + 192]*DIM + qq;
  const __hip_bfloat16* b1P0 = w1e + (size_t)(n0 + rr     )*DIM + qq;
  const __hip_bfloat16* b1P1 = w1e + (size_t)(n0 + rr + 64)*DIM + qq;
  const __hip_bfloat16* b3P0 = w3e + (size_t)(n0 + rr     )*DIM + qq;
  const __hip_bfloat16* b3P1 = w3e + (size_t)(n0 + rr + 64)*DIM + qq;

  int lbase0 = (wav*64)*8, lbase1 = (512 + wav*64)*8;    // wave-uniform LDS short offsets

  auto stageAlo = [&](int t){ int kk = t*64, d = t&1;
    gload16(aP0 + kk, &lA[d][0][0] + lbase0);
    gload16(aP1 + kk, &lA[d][0][0] + lbase1); };
  auto stageAhi = [&](int t){ int kk = t*64, d = t&1;
    gload16(aP2 + kk, &lA[d][128][0] + lbase0);
    gload16(aP3 + kk, &lA[d][128][0] + lbase1); };
  auto stageB1 = [&](int t){ int kk = t*64, d = t&1;
    gload16(b1P0 + kk, &lB1[d][0][0] + lbase0);
    gload16(b1P1 + kk, &lB1[d][0][0] + lbase1); };
  auto stageB3 = [&](int t){ int kk = t*64, d = t&1;
    gload16(b3P0 + kk, &lB3[d][0][0] + lbase0);
    gload16(b3P1 + kk, &lB3[d][0][0] + lbase1); };

  int wm = wav >> 2, wn = wav & 3;           // 2M x 4N waves; per-wave 128 rows x 32 cols/mat
  int lm = lane & 15, lq = lane >> 4;
  int sk = lm & 7;
  int eo0 = ((    lq) ^ sk) * 8;             // ks=0 element offset
  int eo1 = ((4 + lq) ^ sk) * 8;             // ks=1

  v4f acc1[8][2], acc3[8][2];
  v4f vz = {0.f,0.f,0.f,0.f};
  #pragma unroll
  for (int i=0;i<8;i++)
    #pragma unroll
    for (int j=0;j<2;j++){ acc1[i][j]=vz; acc3[i][j]=vz; }

  // prologue: tile0 fully + A[1]; entering loop with A[t+1] outstanding (4 loads)
  stageAlo(0); stageAhi(0); stageB1(0); stageB3(0);
  stageAlo(1); stageAhi(1);
  asm volatile("s_waitcnt vmcnt(4)" ::: "memory");
  __builtin_amdgcn_s_barrier();

  for (int t = 0; t < NT1; ++t){
    int d = t & 1;
    // ---------- P1: read A0 + B1 frags; stage B1[t+1]; MFMA Q(M0,mat1) ----------
    v8bf a0k0[4], a0k1[4], b1k0[2], b1k1[2];
    #pragma unroll
    for (int i=0;i<4;i++){
      a0k0[i] = *reinterpret_cast<const v8bf*>(&lA[d][wm*128 + i*16 + lm][eo0]);
      a0k1[i] = *reinterpret_cast<const v8bf*>(&lA[d][wm*128 + i*16 + lm][eo1]);
    }
    #pragma unroll
    for (int j=0;j<2;j++){
      b1k0[j] = *reinterpret_cast<const v8bf*>(&lB1[d][wn*32 + j*16 + lm][eo0]);
      b1k1[j] = *reinterpret_cast<const v8bf*>(&lB1[d][wn*32 + j*16 + lm][eo1]);
    }
    if (t+1 < NT1) stageB1(t+1);
    __builtin_amdgcn_s_barrier();
    asm volatile("s_waitcnt lgkmcnt(0)" ::: "memory");
    __builtin_amdgcn_s_setprio(1);
    #pragma unroll
    for (int i=0;i<4;i++)
      #pragma unroll
      for (int j=0;j<2;j++){
        acc1[i][j] = __builtin_amdgcn_mfma_f32_16x16x32_bf16(a0k0[i], b1k0[j], acc1[i][j], 0,0,0);
        acc1[i][j] = __builtin_amdgcn_mfma_f32_16x16x32_bf16(a0k1[i], b1k1[j], acc1[i][j], 0,0,0);
      }
    __builtin_amdgcn_s_setprio(0);
    __builtin_amdgcn_s_barrier();

    // ---------- P2: read A1 frags; stage B3[t+1]; MFMA Q(M1,mat1) ----------
    v8bf a1k0[4], a1k1[4];
    #pragma unroll
    for (int i=0;i<4;i++){
      a1k0[i] = *reinterpret_cast<const v8bf*>(&lA[d][wm*128 + 64 + i*16 + lm][eo0]);
      a1k1[i] = *reinterpret_cast<const v8bf*>(&lA[d][wm*128 + 64 + i*16 + lm][eo1]);
    }
    if (t+1 < NT1) stageB3(t+1);
    __builtin_amdgcn_s_barrier();
    asm volatile("s_waitcnt lgkmcnt(0)" ::: "memory");
    __builtin_amdgcn_s_setprio(1);
    #pragma unroll
    for (int i=0;i<4;i++)
      #pragma unroll
      for (int j=0;j<2;j++){
        acc1[4+i][j] = __builtin_amdgcn_mfma_f32_16x16x32_bf16(a1k0[i], b1k0[j], acc1[4+i][j], 0,0,0);
        acc1[4+i][j] = __builtin_amdgcn_mfma_f32_16x16x32_bf16(a1k1[i], b1k1[j], acc1[4+i][j], 0,0,0);
      }
    __builtin_amdgcn_s_setprio(0);
    __builtin_amdgcn_s_barrier();

    // ---------- P3: read B3 frags; stage A-lo[t+2]; MFMA Q(M1,mat3) ----------
    v8bf b3k0[2], b3k1[2];
    #pragma unroll
    for (int j=0;j<2;j++){
      b3k0[j] = *reinterpret_cast<const v8bf*>(&lB3[d][wn*32 + j*16 + lm][eo0]);
      b3k1[j] = *reinterpret_cast<const v8bf*>(&lB3[d][wn*32 + j*16 + lm][eo1]);
    }
    if (t+2 < NT1) stageAlo(t+2);
    __builtin_amdgcn_s_barrier();
    asm volatile("s_waitcnt lgkmcnt(0)" ::: "memory");
    __builtin_amdgcn_s_setprio(1);
    #pragma unroll
    for (int i=0;i<4;i++)
      #pragma unroll
      for (int j=0;j<2;j++){
        acc3[4+i][j] = __builtin_amdgcn_mfma_f32_16x16x32_bf16(a1k0[i], b3k0[j], acc3[4+i][j], 0,0,0);
        acc3[4+i][j] = __builtin_amdgcn_mfma_f32_16x16x32_bf16(a1k1[i], b3k1[j], acc3[4+i][j], 0,0,0);
      }
    __builtin_amdgcn_s_setprio(0);
    __builtin_amdgcn_s_barrier();

    // ---------- P4: stage A-hi[t+2]; MFMA Q(M0,mat3); tile-end counted wait ----------
    if (t+2 < NT1) stageAhi(t+2);
    __builtin_amdgcn_s_barrier();
    __builtin_amdgcn_s_setprio(1);
    #pragma unroll
    for (int i=0;i<4;i++)
      #pragma unroll
      for (int j=0;j<2;j++){
        acc3[i][j] = __builtin_amdgcn_mfma_f32_16x16x32_bf16(a0k0[i], b3k0[j], acc3[i][j], 0,0,0);
        acc3[i][j] = __builtin_amdgcn_mfma_f32_16x16x32_bf16(a0k1[i], b3k1[j], acc3[i][j], 0,0,0);
      }
    __builtin_amdgcn_s_setprio(0);
    if (t+2 < NT1) asm volatile("s_waitcnt vmcnt(4)" ::: "memory");
    else           asm volatile("s_waitcnt vmcnt(0)" ::: "memory");
    __builtin_amdgcn_s_barrier();
  }

  // epilogue: D layout col=lane&15, row=(lane>>4)*4+reg  [m89-verified]
  #pragma unroll
  for (int i=0;i<8;i++){
    #pragma unroll
    for (int r=0;r<4;r++){
      int ml = wm*128 + i*16 + lq*4 + r;
      if (m0 + ml < cnt){
        size_t grow = (size_t)(base + m0 + ml) * HID_PAD;
        #pragma unroll
        for (int j=0;j<2;j++){
          float s1 = acc1[i][j][r];
          float s3 = acc3[i][j][r];
          float gv = (s1 / (1.0f + __expf(-s1))) * s3;   // silu(s1)*s3
          g[grow + n0 + wn*32 + j*16 + lm] = __float2bfloat16(gv);
        }
      }
    }
  }
}

// ---------------- GEMM2: y[row] = weight * (g[row] @ w2) ----------------
// Pure 256x256 8-phase template. Same ledger: P1->B-lo[t+1], P2->B-hi[t+1],
// P3->A-lo[t+2], P4->A-hi[t+2]; tile-end vmcnt(4).

#define BM2 256
#define BN2 256
#define NT2 44   // HID_PAD/64

__global__ __launch_bounds__(512, 2) void moe_gemm2(
    const __hip_bfloat16* __restrict__ g,     // [NROWS][HID_PAD]
    const __hip_bfloat16* __restrict__ w2t,   // [9][DIM][HID_PAD]  (B^T)
    const float* __restrict__ row_weight,
    const int* __restrict__ base_,
    float* __restrict__ y)                    // [NROWS][DIM] scratch (aliases w1t/w3t)
{
  int e = blockIdx.z;
  int base = base_[e];
  int cnt  = base_[e+1] - base;
  int m0 = blockIdx.y * BM2;
  if (m0 >= cnt) return;
  int n0 = blockIdx.x * BN2;

  __shared__ __align__(16) unsigned short lA[2][BM2][64];   // 64 KB
  __shared__ __align__(16) unsigned short lB[2][BN2][64];   // 64 KB
  __shared__ float wgt[BM2];

  int tid = threadIdx.x;
  if (tid < BM2){
    int r = m0 + tid;
    wgt[tid] = (r < cnt) ? row_weight[base + r] : 0.0f;
  }
  __syncthreads();

  const __hip_bfloat16* w2e = w2t + (size_t)e*DIM*HID_PAD;
  int wav = tid >> 6, lane = tid & 63;

  int rr = (wav*64 + lane) >> 3;
  int qq = (((wav*64 + lane) & 7) ^ (rr & 7)) * 8;

  // A over-reach rows land in later valid rows of g; results discarded at store
  const __hip_bfloat16* aP0 = g + (size_t)(base + m0 + rr      )*HID_PAD + qq;
  const __hip_bfloat16* aP1 = g + (size_t)(base + m0 + rr +  64)*HID_PAD + qq;
  const __hip_bfloat16* aP2 = g + (size_t)(base + m0 + rr + 128)*HID_PAD + qq;
  const __hip_bfloat16* aP3 = g + (size_t)(base + m0 + rr + 192)*HID_PAD + qq;
  const __hip_bfloat16* bP0 = w2e + (size_t)(n0 + rr      )*HID_PAD + qq;
  const __hip_bfloat16* bP1 = w2e + (size_t)(n0 + rr +  64)*HID_PAD + qq;
  const __hip_bfloat16* bP2 = w2e + (size_t)(n0 + rr + 128)*HID_PAD + qq;
  const __hip_bfloat16* bP3 = w2e + (size_t)(n0 + rr + 192)*HID_PAD + qq;

  int lbase0 = (wav*64)*8, lbase1 = (512 + wav*64)*8;

  auto stageAlo = [&](int t){ int kk = t*64, d = t&1;
    gload16(aP0 + kk, &lA[d][0][0] + lbase0);
    gload16(aP1 + kk, &lA[d][0][0] + lbase1); };
  auto stageAhi = [&](int t){ int kk = t*64, d = t&1;
    gload16(aP2 + kk, &lA[d][128][0] + lbase0);
    gload16(aP3 + kk, &lA[d][128][0] + lbase1); };
  auto stageBlo = [&](int t){ int kk = t*64, d = t&1;
    gload16(bP0 + kk, &lB[d][0][0] + lbase0);
    gload16(bP1 + kk, &lB[d][0][0] + lbase1); };
  auto stageBhi = [&](int t){ int kk = t*64, d = t&1;
    gload16(bP2 + kk, &lB[d][128][0] + lbase0);
    gload16(bP3 + kk, &lB[d][128][0] + lbase1); };

  int wm = wav >> 2, wn = wav & 3;           // per-wave 128 rows x 64 cols
  int lm = lane & 15, lq = lane >> 4;
  int sk = lm & 7;
  int eo0 = ((    lq) ^ sk) * 8;
  int eo1 = ((4 + lq) ^ sk) * 8;

  v4f acc[8][4];
  v4f vz = {0.f,0.f,0.f,0.f};
  #pragma unroll
  for (int i=0;i<8;i++)
    #pragma unroll
    for (int j=0;j<4;j++) acc[i][j]=vz;

  stageAlo(0); stageAhi(0); stageBlo(0); stageBhi(0);
  stageAlo(1); stageAhi(1);
  asm volatile("s_waitcnt vmcnt(4)" ::: "memory");
  __builtin_amdgcn_s_barrier();

  for (int t = 0; t < NT2; ++t){
    int d = t & 1;
    // ---------- P1: read A0 + B(j=0,1); stage B-lo[t+1]; Q(M0,N01) ----------
    v8bf a0k0[4], a0k1[4], bAk0[2], bAk1[2];
    #pragma unroll
    for (int i=0;i<4;i++){
      a0k0[i] = *reinterpret_cast<const v8bf*>(&lA[d][wm*128 + i*16 + lm][eo0]);
      a0k1[i] = *reinterpret_cast<const v8bf*>(&lA[d][wm*128 + i*16 + lm][eo1]);
    }
    #pragma unroll
    for (int j=0;j<2;j++){
      bAk0[j] = *reinterpret_cast<const v8bf*>(&lB[d][wn*64 + j*16 + lm][eo0]);
      bAk1[j] = *reinterpret_cast<const v8bf*>(&lB[d][wn*64 + j*16 + lm][eo1]);
    }
    if (t+1 < NT2) stageBlo(t+1);
    __builtin_amdgcn_s_barrier();
    asm volatile("s_waitcnt lgkmcnt(0)" ::: "memory");
    __builtin_amdgcn_s_setprio(1);
    #pragma unroll
    for (int i=0;i<4;i++)
      #pragma unroll
      for (int j=0;j<2;j++){
        acc[i][j] = __builtin_amdgcn_mfma_f32_16x16x32_bf16(a0k0[i], bAk0[j], acc[i][j], 0,0,0);
        acc[i][j] = __builtin_amdgcn_mfma_f32_16x16x32_bf16(a0k1[i], bAk1[j], acc[i][j], 0,0,0);
      }
    __builtin_amdgcn_s_setprio(0);
    __builtin_amdgcn_s_barrier();

    // ---------- P2: read A1; stage B-hi[t+1]; Q(M1,N01) ----------
    v8bf a1k0[4], a1k1[4];
    #pragma unroll
    for (int i=0;i<4;i++){
      a1k0[i] = *reinterpret_cast<const v8bf*>(&lA[d][wm*128 + 64 + i*16 + lm][eo0]);
      a1k1[i] = *reinterpret_cast<const v8bf*>(&lA[d][wm*128 + 64 + i*16 + lm][eo1]);
    }
    if (t+1 < NT2) stageBhi(t+1);
    __builtin_amdgcn_s_barrier();
    asm volatile("s_waitcnt lgkmcnt(0)" ::: "memory");
    __builtin_amdgcn_s_setprio(1);
    #pragma unroll
    for (int i=0;i<4;i++)
      #pragma unroll
      for (int j=0;j<2;j++){
        acc[4+i][j] = __builtin_amdgcn_mfma_f32_16x16x32_bf16(a1k0[i], bAk0[j], acc[4+i][j], 0,0,0);
        acc[4+i][j] = __builtin_amdgcn_mfma_f32_16x16x32_bf16(a1k1[i], bAk1[j], acc[4+i][j], 0,0,0);
      }
    __builtin_amdgcn_s_setprio(0);
    __builtin_amdgcn_s_barrier();

    // ---------- P3: read B(j=2,3); stage A-lo[t+2]; Q(M1,N23) ----------
    v8bf bBk0[2], bBk1[2];
    #pragma unroll
    for (int j=0;j<2;j++){
      bBk0[j] = *reinterpret_cast<const v8bf*>(&lB[d][wn*64 + 32 + j*16 + lm][eo0]);
      bBk1[j] = *reinterpret_cast<const v8bf*>(&lB[d][wn*64 + 32 + j*16 + lm][eo1]);
    }
    if (t+2 < NT2) stageAlo(t+2);
    __builtin_amdgcn_s_barrier();
    asm volatile("s_waitcnt lgkmcnt(0)" ::: "memory");
    __builtin_amdgcn_s_setprio(1);
    #pragma unroll
    for (int i=0;i<4;i++)
      #pragma unroll
      for (int j=0;j<2;j++){
        acc[4+i][2+j] = __builtin_amdgcn_mfma_f32_16x16x32_bf16(a1k0[i], bBk0[j], acc[4+i][2+j], 0,0,0);
        acc[4+i][2+j] = __builtin_amdgcn_mfma_f32_16x16x32_bf16(a1k1[i], bBk1[j], acc[4+i][2+j], 0,0,0);
      }
    __builtin_amdgcn_s_setprio(0);
    __builtin_amdgcn_s_barrier();

    // ---------- P4: stage A-hi[t+2]; Q(M0,N23); tile-end counted wait ----------
    if (t+2 < NT2) stageAhi(t+2);
    __builtin_amdgcn_s_barrier();
    __builtin_amdgcn_s_setprio(1);
    #pragma unroll
    for (int i=0;i<4;i++)
      #pragma unroll
      for (int j=0;j<2;j++){
        acc[i][2+j] = __builtin_amdgcn_mfma_f32_16x16x32_bf16(a0k0[i], bBk0[j], acc[i][2+j], 0,0,0);
        acc[i][2+j] = __builtin_amdgcn_mfma_f32_16x16x32_bf16(a0k1[i], bBk1[j], acc[i][2+j], 0,0,0);
      }
    __builtin_amdgcn_s_setprio(0);
    if (t+2 < NT2) asm volatile("s_waitcnt vmcnt(4)" ::: "memory");
    else           asm volatile("s_waitcnt vmcnt(0)" ::: "memory");
    __builtin_amdgcn_s_barrier();
  }

  #pragma unroll
  for (int i=0;i<8;i++){
    #pragma unroll
    for (int r=0;r<4;r++){
      int ml = wm*128 + i*16 + lq*4 + r;
      if (m0 + ml < cnt){
        float wv = wgt[ml];
        size_t yrow = (size_t)(base + m0 + ml) * DIM;
        #pragma unroll
        for (int j=0;j<4;j++)
          y[yrow + n0 + wn*64 + j*16 + lm] = wv * acc[i][j][r];
      }
    }
  }
}

// ---------------- combine: out[t] = y[shared_t] + y[r0] + y[r1] (y pre-weighted) ----------------

__global__ __launch_bounds__(256) void moe_combine(
    const float4* __restrict__ y, const int* __restrict__ inv, float4* __restrict__ out){
  int idx = blockIdx.x*blockDim.x + threadIdx.x;   // 8192 * 512
  int t = idx >> 9, d = idx & 511;
  float4 s = y[(((size_t)16384 + t) << 9) + d];
  int r0 = inv[t*2], r1 = inv[t*2+1];
  float4 a = y[((size_t)r0 << 9) + d];
  float4 b = y[((size_t)r1 << 9) + d];
  s.x += a.x + b.x; s.y += a.y + b.y; s.z += a.z + b.z; s.w += a.w + b.w;
  out[idx] = s;
}

// ---------------- host launch ----------------

extern "C" void kernel_launch(void* const* d_in, const int* in_sizes, int n_in,
                              void* d_out, int out_size, void* d_ws, size_t ws_size,
                              hipStream_t stream) {
  const float* x   = (const float*)d_in[0];
  const float* rw  = (const float*)d_in[1];
  const float* sw1 = (const float*)d_in[2];
  const float* sw2 = (const float*)d_in[3];
  const float* sw3 = (const float*)d_in[4];
  const float* ew1 = (const float*)d_in[5];
  const float* ew2 = (const float*)d_in[6];
  const float* ew3 = (const float*)d_in[7];
  float* out = (float*)d_out;

  char* ws = (char*)d_ws;
  size_t off = 0;
  auto nxt = [&](size_t b) -> char* {
    char* p = ws + off; off += (b + 255) & ~(size_t)255; return p;
  };
  __hip_bfloat16* xb  = (__hip_bfloat16*)nxt((size_t)NTOK*DIM*2);          // 33.5 MB
  __hip_bfloat16* w1t = (__hip_bfloat16*)nxt((size_t)9*HID_PAD*DIM*2);     // 103.8 MB
  __hip_bfloat16* w3t = (__hip_bfloat16*)nxt((size_t)9*HID_PAD*DIM*2);     // 103.8 MB
  __hip_bfloat16* w2t = (__hip_bfloat16*)nxt((size_t)9*DIM*HID_PAD*2);     // 103.8 MB
  __hip_bfloat16* g   = (__hip_bfloat16*)nxt((size_t)NROWS*HID_PAD*2);     // 138.4 MB
  float* topw      = (float*)nxt(16384*4);
  int*   cnt       = (int*)  nxt(32);
  int*   base_     = (int*)  nxt(64);
  int*   bucket    = (int*)  nxt(NE*16384*4);
  int*   row_token = (int*)  nxt(NROWS*4);
  float* row_weight= (float*)nxt(NROWS*4);
  int*   inv       = (int*)  nxt(16384*4);

  // y scratch (201.3 MB fp32) aliases w1t/w3t (207.6 MB) — dead after gemm1,
  // written by gemm2, read by combine; stream-ordered so no hazard.
  static_assert((size_t)NROWS*DIM*4 <= 2*((size_t)9*HID_PAD*DIM*2), "y alias overflow");
  float* y = (float*)w1t;

  if (off > ws_size) {
    fprintf(stderr, "MoE kernel: ws too small (%zu needed, %zu given)\n", off, ws_size);
    return;
  }

  moe_zero_i<<<1, 32, 0, stream>>>(cnt, NE);
  moe_cast_x<<<16384, 256, 0, stream>>>(x, xb);

  dim3 tb(32,8);
  moe_tcast<<<dim3(88,64,9), tb, 0, stream>>>(ew1, sw1, w1t, DIM, HID, HID_PAD, DIM);
  moe_tcast<<<dim3(88,64,9), tb, 0, stream>>>(ew3, sw3, w3t, DIM, HID, HID_PAD, DIM);
  moe_tcast<<<dim3(64,88,9), tb, 0, stream>>>(ew2, sw2, w2t, HID, DIM, DIM, HID_PAD);

  moe_router<<<NTOK/4, 256, 0, stream>>>(x, rw, topw, cnt, bucket);
  moe_prefix<<<1, 1, 0, stream>>>(cnt, base_);
  moe_fill<<<544, 256, 0, stream>>>(cnt, base_, bucket, topw, row_token, row_weight, inv);

  moe_gemm1<<<dim3(22,32,9), 512, 0, stream>>>(xb, w1t, w3t, row_token, base_, g);
  moe_gemm2<<<dim3(8,32,9), 512, 0, stream>>>(g, w2t, row_weight, base_, y);
  moe_combine<<<16384, 256, 0, stream>>>((const float4*)y, inv, (float4*)out);
}